// Round 3
// baseline (467.361 us; speedup 1.0000x reference)
//
#include <hip/hip_runtime.h>

typedef __bf16 bf16;
typedef __bf16 bf16x8 __attribute__((ext_vector_type(8)));
typedef float f32x4 __attribute__((ext_vector_type(4)));

#define DM 1024
#define NH 16
#define DKK 64
#define BB 4
#define SS 2048
#define MTOT (BB * SS)

__device__ __forceinline__ f32x4 mfma16(bf16x8 a, bf16x8 b, f32x4 c) {
  return __builtin_amdgcn_mfma_f32_16x16x32_bf16(a, b, c, 0, 0, 0);
}

// ---------------- f32 -> bf16 conversion (vectorized, 8 elems/thread) -------
__global__ void cvt_kernel(const float* __restrict__ in, bf16* __restrict__ out) {
  long i = (long)(blockIdx.x * blockDim.x + threadIdx.x) * 8;
  float4 a = *reinterpret_cast<const float4*>(in + i);
  float4 b = *reinterpret_cast<const float4*>(in + i + 4);
  bf16x8 o;
  o[0] = (bf16)a.x; o[1] = (bf16)a.y; o[2] = (bf16)a.z; o[3] = (bf16)a.w;
  o[4] = (bf16)b.x; o[5] = (bf16)b.y; o[6] = (bf16)b.z; o[7] = (bf16)b.w;
  *reinterpret_cast<bf16x8*>(out + i) = o;
}

// ---------------- W[k][n] f32 -> Wt[n][k] bf16 (tiled transpose) ------------
__global__ void transpose_cvt_kernel(const float* __restrict__ w0, const float* __restrict__ w1,
                                     const float* __restrict__ w2, const float* __restrict__ w3,
                                     bf16* __restrict__ o0, bf16* __restrict__ o1,
                                     bf16* __restrict__ o2, bf16* __restrict__ o3) {
  __shared__ float t[32][33];
  int z = blockIdx.z;
  const float* src = z == 0 ? w0 : z == 1 ? w1 : z == 2 ? w2 : w3;
  bf16* dst = z == 0 ? o0 : z == 1 ? o1 : z == 2 ? o2 : o3;
  int n0 = blockIdx.x * 32, k0 = blockIdx.y * 32;
  int tx = threadIdx.x, ty = threadIdx.y;  // (32, 8)
#pragma unroll
  for (int j = 0; j < 4; ++j)
    t[ty + 8 * j][tx] = src[(long)(k0 + ty + 8 * j) * DM + n0 + tx];
  __syncthreads();
#pragma unroll
  for (int j = 0; j < 4; ++j)
    dst[(long)(n0 + ty + 8 * j) * DM + k0 + tx] = (bf16)t[tx][ty + 8 * j];
}

// ---------------- 128x128x32 bf16 MFMA GEMM: C = A @ Wt^T + bias ------------
// A: [M, 1024] bf16 row-major.  Bt: [1024(N), 1024(K)] bf16 row-major (W^T).
// MODE 0: store bf16 at [B,H,S,dk]   (Q, K)
// MODE 1: store bf16 at [B,H,dk,S]   (V transposed)
// MODE 2: store f32 row-major [M, N] (final output)
template <int MODE>
__global__ __launch_bounds__(256, 2) void gemm_kernel(const bf16* __restrict__ A,
                                                      const bf16* __restrict__ Bt,
                                                      const float* __restrict__ bias,
                                                      void* __restrict__ Cout) {
  const int LDT = 40;  // 32 + 8 pad, keeps rows 16B-aligned, breaks bank conflicts
  __shared__ bf16 As[2][128 * LDT];
  __shared__ bf16 Bs[2][128 * LDT];
  int tid = threadIdx.x;
  int m0 = blockIdx.x * 128, n0 = blockIdx.y * 128;
  int lane = tid & 63, wid = tid >> 6;
  int wr = wid >> 1, wc = wid & 1;
  int lo = lane & 15, hi = lane >> 4;
  int r0 = tid >> 2, c0 = (tid & 3) * 8;
  const bf16* Ap = A + (long)(m0 + r0) * DM + c0;
  const bf16* Bp = Bt + (long)(n0 + r0) * DM + c0;
  int lA = r0 * LDT + c0;
  int lA2 = (r0 + 64) * LDT + c0;

  f32x4 acc[4][4] = {};

  // prologue: stage tile 0
  int4 ra0 = *(const int4*)Ap;
  int4 ra1 = *(const int4*)(Ap + 64 * DM);
  int4 rb0 = *(const int4*)Bp;
  int4 rb1 = *(const int4*)(Bp + 64 * DM);
  *(int4*)&As[0][lA] = ra0; *(int4*)&As[0][lA2] = ra1;
  *(int4*)&Bs[0][lA] = rb0; *(int4*)&Bs[0][lA2] = rb1;
  __syncthreads();

  int buf = 0;
  for (int kt = 0; kt < 32; ++kt) {
    int4 na0, na1, nb0, nb1;
    bool more = (kt + 1) < 32;
    if (more) {
      const bf16* Ap2 = Ap + (kt + 1) * 32;
      const bf16* Bp2 = Bp + (kt + 1) * 32;
      na0 = *(const int4*)Ap2; na1 = *(const int4*)(Ap2 + 64 * DM);
      nb0 = *(const int4*)Bp2; nb1 = *(const int4*)(Bp2 + 64 * DM);
    }
    bf16x8 af[4], bfr[4];
#pragma unroll
    for (int mi = 0; mi < 4; ++mi)
      af[mi] = *(const bf16x8*)&As[buf][(wr * 64 + mi * 16 + lo) * LDT + hi * 8];
#pragma unroll
    for (int ni = 0; ni < 4; ++ni)
      bfr[ni] = *(const bf16x8*)&Bs[buf][(wc * 64 + ni * 16 + lo) * LDT + hi * 8];
#pragma unroll
    for (int mi = 0; mi < 4; ++mi)
#pragma unroll
      for (int ni = 0; ni < 4; ++ni)
        acc[mi][ni] = mfma16(af[mi], bfr[ni], acc[mi][ni]);
    if (more) {
      *(int4*)&As[buf ^ 1][lA] = na0; *(int4*)&As[buf ^ 1][lA2] = na1;
      *(int4*)&Bs[buf ^ 1][lA] = nb0; *(int4*)&Bs[buf ^ 1][lA2] = nb1;
    }
    __syncthreads();
    buf ^= 1;
  }

  // epilogue: bias + scatter store
#pragma unroll
  for (int ni = 0; ni < 4; ++ni) {
    int col = n0 + wc * 64 + ni * 16 + lo;
    float bv = bias[col];
#pragma unroll
    for (int mi = 0; mi < 4; ++mi) {
      int rowb = m0 + wr * 64 + mi * 16 + hi * 4;
#pragma unroll
      for (int r = 0; r < 4; ++r) {
        int row = rowb + r;
        float v = acc[mi][ni][r] + bv;
        if (MODE == 0) {
          int b = row >> 11, s = row & 2047, h = col >> 6, d = col & 63;
          ((bf16*)Cout)[(((long)(b * NH + h) * SS + s) << 6) | d] = (bf16)v;
        } else if (MODE == 1) {
          int b = row >> 11, s = row & 2047, h = col >> 6, d = col & 63;
          ((bf16*)Cout)[(((long)(b * NH + h) * DKK + d) << 11) | s] = (bf16)v;
        } else {
          ((float*)Cout)[(long)row * DM + col] = v;
        }
      }
    }
  }
}

// ---------------- causal flash attention --------------------------------------
// Q,K: [B,H,S,64] bf16.  VT: [B,H,64,S] bf16.  AO: [B,S,H*64] bf16.
// grid (B*H, S/64); 4 waves/block, each wave owns 16 query rows.
__global__ __launch_bounds__(256, 2) void attn_kernel(const bf16* __restrict__ Q,
                                                      const bf16* __restrict__ K,
                                                      const bf16* __restrict__ VT,
                                                      bf16* __restrict__ AO) {
  __shared__ bf16 Pl[4][16 * 40];
  int bh = blockIdx.x, qt = blockIdx.y;
  int tid = threadIdx.x, wid = tid >> 6, lane = tid & 63;
  int lo = lane & 15, hi = lane >> 4;
  int q0 = qt * 64 + wid * 16;
  const bf16* Qh = Q + (long)bh * SS * DKK;
  const bf16* Kh = K + (long)bh * SS * DKK;
  const bf16* Vh = VT + (long)bh * DKK * SS;
  bf16* Pw = Pl[wid];

  bf16x8 qf0 = *(const bf16x8*)&Qh[(q0 + lo) * DKK + hi * 8];
  bf16x8 qf1 = *(const bf16x8*)&Qh[(q0 + lo) * DKK + 32 + hi * 8];

  f32x4 o[4] = {};
  float mrun[4] = {-1e30f, -1e30f, -1e30f, -1e30f};
  float lrun[4] = {};

  int ntiles = (q0 + 15) / 32 + 1;
  for (int t = 0; t < ntiles; ++t) {
    int kb = t * 32;
    // QK^T: scores 16x32 (two 16x16 frags)
    bf16x8 k00 = *(const bf16x8*)&Kh[(kb + lo) * DKK + hi * 8];
    bf16x8 k01 = *(const bf16x8*)&Kh[(kb + lo) * DKK + 32 + hi * 8];
    bf16x8 k10 = *(const bf16x8*)&Kh[(kb + 16 + lo) * DKK + hi * 8];
    bf16x8 k11 = *(const bf16x8*)&Kh[(kb + 16 + lo) * DKK + 32 + hi * 8];
    f32x4 z = {0.f, 0.f, 0.f, 0.f};
    f32x4 s0 = mfma16(qf1, k01, mfma16(qf0, k00, z));
    f32x4 s1 = mfma16(qf1, k11, mfma16(qf0, k10, z));

    // scale + causal mask + row max
    float pm[4];
#pragma unroll
    for (int r = 0; r < 4; ++r) {
      int qrow = q0 + hi * 4 + r;
      float a0 = (kb + lo <= qrow) ? s0[r] * 0.125f : -1e30f;
      float a1 = (kb + 16 + lo <= qrow) ? s1[r] * 0.125f : -1e30f;
      s0[r] = a0; s1[r] = a1;
      pm[r] = fmaxf(a0, a1);
    }
#pragma unroll
    for (int m = 1; m < 16; m <<= 1)
#pragma unroll
      for (int r = 0; r < 4; ++r) pm[r] = fmaxf(pm[r], __shfl_xor(pm[r], m, 64));

    // online softmax update; stage P (bf16) to LDS in transposed-read layout
    float rs[4];
#pragma unroll
    for (int r = 0; r < 4; ++r) {
      float mnew = fmaxf(mrun[r], pm[r]);
      float corr = __expf(mrun[r] - mnew);
      mrun[r] = mnew;
      lrun[r] *= corr;
#pragma unroll
      for (int df = 0; df < 4; ++df) o[df][r] *= corr;
      float p0 = __expf(s0[r] - mnew);
      float p1 = __expf(s1[r] - mnew);
      rs[r] = p0 + p1;
      int rr = hi * 4 + r;
      Pw[rr * 40 + lo] = (bf16)p0;
      Pw[rr * 40 + 16 + lo] = (bf16)p1;
    }
#pragma unroll
    for (int m = 1; m < 16; m <<= 1)
#pragma unroll
      for (int r = 0; r < 4; ++r) rs[r] += __shfl_xor(rs[r], m, 64);
#pragma unroll
    for (int r = 0; r < 4; ++r) lrun[r] += rs[r];

    // PV: A-frag = P (read back transposed), B-frag = rows of VT
    bf16x8 pf = *(const bf16x8*)&Pw[lo * 40 + hi * 8];
#pragma unroll
    for (int df = 0; df < 4; ++df) {
      bf16x8 vf = *(const bf16x8*)&Vh[(df * 16 + lo) * SS + kb + hi * 8];
      o[df] = mfma16(pf, vf, o[df]);
    }
  }

  int b = bh >> 4, h = bh & 15;
#pragma unroll
  for (int df = 0; df < 4; ++df)
#pragma unroll
    for (int r = 0; r < 4; ++r) {
      int q = q0 + hi * 4 + r;
      AO[(long)(b * SS + q) * DM + h * DKK + df * 16 + lo] = (bf16)(o[df][r] / lrun[r]);
    }
}

// ---------------- launcher ----------------------------------------------------
extern "C" void kernel_launch(void* const* d_in, const int* in_sizes, int n_in,
                              void* d_out, int out_size, void* d_ws, size_t ws_size,
                              hipStream_t stream) {
  // Workspace guard: we need 72 MB of scratch. If the harness provides less,
  // skip cleanly (correctness will fail against a zeroed output, but the
  // container survives and tells us to restructure memory).
  if (ws_size < (72ULL << 20)) return;

  const float* x  = (const float*)d_in[0];
  const float* Wq = (const float*)d_in[1];
  const float* bq = (const float*)d_in[2];
  const float* Wk = (const float*)d_in[3];
  const float* bk = (const float*)d_in[4];
  const float* Wv = (const float*)d_in[5];
  const float* bv = (const float*)d_in[6];
  const float* Wo = (const float*)d_in[7];
  const float* bo = (const float*)d_in[8];

  char* ws = (char*)d_ws;
  bf16* xb  = (bf16*)(ws);                     // 16 MB (later reused as AO)
  bf16* wtq = (bf16*)(ws + (16L << 20));       // 2 MB each
  bf16* wtk = (bf16*)(ws + (18L << 20));
  bf16* wtv = (bf16*)(ws + (20L << 20));
  bf16* wto = (bf16*)(ws + (22L << 20));
  bf16* Qb  = (bf16*)(ws + (24L << 20));       // 16 MB
  bf16* Kb  = (bf16*)(ws + (40L << 20));       // 16 MB
  bf16* VTb = (bf16*)(ws + (56L << 20));       // 16 MB
  bf16* AO  = xb;                              // alias: x_bf16 dead after QKV GEMMs

  cvt_kernel<<<(MTOT * DM) / (256 * 8), 256, 0, stream>>>(x, xb);
  transpose_cvt_kernel<<<dim3(32, 32, 4), dim3(32, 8), 0, stream>>>(
      Wq, Wk, Wv, Wo, wtq, wtk, wtv, wto);

  gemm_kernel<0><<<dim3(64, 8), 256, 0, stream>>>(xb, wtq, bq, (void*)Qb);
  gemm_kernel<0><<<dim3(64, 8), 256, 0, stream>>>(xb, wtk, bk, (void*)Kb);
  gemm_kernel<1><<<dim3(64, 8), 256, 0, stream>>>(xb, wtv, bv, (void*)VTb);

  attn_kernel<<<dim3(64, 32), 256, 0, stream>>>(Qb, Kb, VTb, AO);

  gemm_kernel<2><<<dim3(64, 8), 256, 0, stream>>>(AO, wto, bo, d_out);
}

// Round 8
// 417.526 us; speedup vs baseline: 1.1194x; 1.1194x over previous
//
#include <hip/hip_runtime.h>

typedef __bf16 bf16;
typedef __bf16 bf16x8 __attribute__((ext_vector_type(8)));
typedef float f32x4 __attribute__((ext_vector_type(4)));

#define DM 1024
#define NH 16
#define DKK 64
#define BB 4
#define SS 2048
#define MTOT (BB * SS)
// softmax scale folded into Q: 1/sqrt(dk) * log2(e)  (exp2-direct domain)
#define QSC 0.18033688011112042f

__device__ __forceinline__ f32x4 mfma16(bf16x8 a, bf16x8 b, f32x4 c) {
  return __builtin_amdgcn_mfma_f32_16x16x32_bf16(a, b, c, 0, 0, 0);
}

// P-LDS swizzle: row stride 128 B; XOR row-dependent bits into byte offset
// so the 16-lane b128 column reads spread across all banks.
__device__ __forceinline__ int pswz(int row, int colbyte) {
  return row * 128 + (colbyte ^ ((row & 7) << 4));
}

// ---------------- f32 -> bf16 conversion (vectorized, 8 elems/thread) -------
__global__ void cvt_kernel(const float* __restrict__ in, bf16* __restrict__ out) {
  long i = (long)(blockIdx.x * blockDim.x + threadIdx.x) * 8;
  float4 a = *reinterpret_cast<const float4*>(in + i);
  float4 b = *reinterpret_cast<const float4*>(in + i + 4);
  bf16x8 o;
  o[0] = (bf16)a.x; o[1] = (bf16)a.y; o[2] = (bf16)a.z; o[3] = (bf16)a.w;
  o[4] = (bf16)b.x; o[5] = (bf16)b.y; o[6] = (bf16)b.z; o[7] = (bf16)b.w;
  *reinterpret_cast<bf16x8*>(out + i) = o;
}

// ---------------- W[k][n] f32 -> Wt[n][k] bf16 (tiled transpose) ------------
__global__ void transpose_cvt_kernel(const float* __restrict__ w0, const float* __restrict__ w1,
                                     const float* __restrict__ w2, const float* __restrict__ w3,
                                     bf16* __restrict__ o0, bf16* __restrict__ o1,
                                     bf16* __restrict__ o2, bf16* __restrict__ o3) {
  __shared__ float t[32][33];
  int z = blockIdx.z;
  const float* src = z == 0 ? w0 : z == 1 ? w1 : z == 2 ? w2 : w3;
  bf16* dst = z == 0 ? o0 : z == 1 ? o1 : z == 2 ? o2 : o3;
  int n0 = blockIdx.x * 32, k0 = blockIdx.y * 32;
  int tx = threadIdx.x, ty = threadIdx.y;  // (32, 8)
#pragma unroll
  for (int j = 0; j < 4; ++j)
    t[ty + 8 * j][tx] = src[(long)(k0 + ty + 8 * j) * DM + n0 + tx];
  __syncthreads();
#pragma unroll
  for (int j = 0; j < 4; ++j)
    dst[(long)(n0 + ty + 8 * j) * DM + k0 + tx] = (bf16)t[tx][ty + 8 * j];
}

// ---------------- 128x128x32 bf16 MFMA GEMM: C = (A @ Wt^T + bias)*oscale ---
// MODE 0: store bf16 at [B,H,S,dk]   (Q with oscale=QSC, K with 1.0)
// MODE 1: store bf16 at [B,H,dk,S]   (V transposed)
// MODE 2: store f32 row-major [M, N] (final output)
template <int MODE>
__global__ __launch_bounds__(256, 2) void gemm_kernel(const bf16* __restrict__ A,
                                                      const bf16* __restrict__ Bt,
                                                      const float* __restrict__ bias,
                                                      void* __restrict__ Cout, float oscale) {
  const int LDT = 40;
  __shared__ bf16 As[2][128 * LDT];
  __shared__ bf16 Bs[2][128 * LDT];
  int tid = threadIdx.x;
  int m0 = blockIdx.x * 128, n0 = blockIdx.y * 128;
  int lane = tid & 63, wid = tid >> 6;
  int wr = wid >> 1, wc = wid & 1;
  int lo = lane & 15, hi = lane >> 4;
  int r0 = tid >> 2, c0 = (tid & 3) * 8;
  const bf16* Ap = A + (long)(m0 + r0) * DM + c0;
  const bf16* Bp = Bt + (long)(n0 + r0) * DM + c0;
  int lA = r0 * LDT + c0;
  int lA2 = (r0 + 64) * LDT + c0;

  f32x4 acc[4][4] = {};

  int4 ra0 = *(const int4*)Ap;
  int4 ra1 = *(const int4*)(Ap + 64 * DM);
  int4 rb0 = *(const int4*)Bp;
  int4 rb1 = *(const int4*)(Bp + 64 * DM);
  *(int4*)&As[0][lA] = ra0; *(int4*)&As[0][lA2] = ra1;
  *(int4*)&Bs[0][lA] = rb0; *(int4*)&Bs[0][lA2] = rb1;
  __syncthreads();

  int buf = 0;
  for (int kt = 0; kt < 32; ++kt) {
    int4 na0, na1, nb0, nb1;
    bool more = (kt + 1) < 32;
    if (more) {
      const bf16* Ap2 = Ap + (kt + 1) * 32;
      const bf16* Bp2 = Bp + (kt + 1) * 32;
      na0 = *(const int4*)Ap2; na1 = *(const int4*)(Ap2 + 64 * DM);
      nb0 = *(const int4*)Bp2; nb1 = *(const int4*)(Bp2 + 64 * DM);
    }
    bf16x8 af[4], bfr[4];
#pragma unroll
    for (int mi = 0; mi < 4; ++mi)
      af[mi] = *(const bf16x8*)&As[buf][(wr * 64 + mi * 16 + lo) * LDT + hi * 8];
#pragma unroll
    for (int ni = 0; ni < 4; ++ni)
      bfr[ni] = *(const bf16x8*)&Bs[buf][(wc * 64 + ni * 16 + lo) * LDT + hi * 8];
#pragma unroll
    for (int mi = 0; mi < 4; ++mi)
#pragma unroll
      for (int ni = 0; ni < 4; ++ni)
        acc[mi][ni] = mfma16(af[mi], bfr[ni], acc[mi][ni]);
    if (more) {
      *(int4*)&As[buf ^ 1][lA] = na0; *(int4*)&As[buf ^ 1][lA2] = na1;
      *(int4*)&Bs[buf ^ 1][lA] = nb0; *(int4*)&Bs[buf ^ 1][lA2] = nb1;
    }
    __syncthreads();
    buf ^= 1;
  }

#pragma unroll
  for (int ni = 0; ni < 4; ++ni) {
    int col = n0 + wc * 64 + ni * 16 + lo;
    float bv = bias[col];
#pragma unroll
    for (int mi = 0; mi < 4; ++mi) {
      int rowb = m0 + wr * 64 + mi * 16 + hi * 4;
#pragma unroll
      for (int r = 0; r < 4; ++r) {
        int row = rowb + r;
        float v = (acc[mi][ni][r] + bv) * oscale;
        if (MODE == 0) {
          int b = row >> 11, s = row & 2047, h = col >> 6, d = col & 63;
          ((bf16*)Cout)[(((long)(b * NH + h) * SS + s) << 6) | d] = (bf16)v;
        } else if (MODE == 1) {
          int b = row >> 11, s = row & 2047, h = col >> 6, d = col & 63;
          ((bf16*)Cout)[(((long)(b * NH + h) * DKK + d) << 11) | s] = (bf16)v;
        } else {
          ((float*)Cout)[(long)row * DM + col] = v;
        }
      }
    }
  }
}

// ---------------- causal flash attention (16x16 MFMA, round-3 conventions) ---
// Q (pre-scaled by QSC), K: [B,H,S,64] bf16.  VT: [B,H,64,S] bf16.
// AO: [B,S,1024] bf16.  Grid 1024 blocks x 256 thr; 4 waves x 32 q-rows each;
// KBLK=64 per tile.  D-layout (verified round 3): col=lane&15, row=hi*4+reg.
__global__ __launch_bounds__(256, 2) void attn_kernel(const bf16* __restrict__ Q,
                                                      const bf16* __restrict__ K,
                                                      const bf16* __restrict__ VT,
                                                      bf16* __restrict__ AO) {
  __shared__ char Pl[4][4096];  // per-wave P tile: 32 rows x 128 B, swizzled
  int bid = blockIdx.x;
  int qt = 15 - (bid >> 6);  // longest q-tiles first (causal tail pack)
  int bh = bid & 63;
  int tid = threadIdx.x, wid = tid >> 6, lane = tid & 63;
  int lo = lane & 15, hi = lane >> 4;
  int q0w = qt * 128 + wid * 32;
  const bf16* Qh = Q + (long)bh * SS * DKK;
  const bf16* Kh = K + (long)bh * SS * DKK;
  const bf16* Vh = VT + (long)bh * DKK * SS;
  char* pw = Pl[wid];

  // Q A-frags: qf[b2][c] = Q[q0w + b2*16 + lo][c*32 + hi*8 + j]
  bf16x8 qf[2][2];
#pragma unroll
  for (int b2 = 0; b2 < 2; ++b2)
#pragma unroll
    for (int c = 0; c < 2; ++c)
      qf[b2][c] = *(const bf16x8*)&Qh[(q0w + b2 * 16 + lo) * DKK + c * 32 + hi * 8];

  f32x4 o[4][2] = {};              // [df][b2]
  float mrun[2][4], lrun[2][4];    // [b2][r]
#pragma unroll
  for (int b2 = 0; b2 < 2; ++b2)
#pragma unroll
    for (int r = 0; r < 4; ++r) { mrun[b2][r] = -1e30f; lrun[b2][r] = 0.f; }

  int ntiles = (q0w + 95) >> 6;
  for (int t = 0; t < ntiles; ++t) {
    int kb = t * 64;
    // ---- QK^T: s[b2][kf] covers q-rows (b2*16+hi*4+r), k-cols (kf*16+lo)
    f32x4 s[2][4];
#pragma unroll
    for (int kf = 0; kf < 4; ++kf) {
      const bf16* kp = &Kh[(kb + kf * 16 + lo) * DKK + hi * 8];
      bf16x8 k0 = *(const bf16x8*)kp;
      bf16x8 k1 = *(const bf16x8*)(kp + 32);
#pragma unroll
      for (int b2 = 0; b2 < 2; ++b2) {
        f32x4 z = {0.f, 0.f, 0.f, 0.f};
        s[b2][kf] = mfma16(qf[b2][1], k1, mfma16(qf[b2][0], k0, z));
      }
    }

    if (t == ntiles - 1) {  // diagonal tile: causal mask
#pragma unroll
      for (int b2 = 0; b2 < 2; ++b2)
#pragma unroll
        for (int kf = 0; kf < 4; ++kf) {
          int kcol = kb + kf * 16 + lo;
#pragma unroll
          for (int r = 0; r < 4; ++r) {
            int qrow = q0w + b2 * 16 + hi * 4 + r;
            if (kcol > qrow) s[b2][kf][r] = -1e30f;
          }
        }
    }

    // ---- row max over 64 k: local fmax across kf, then 4-level shfl_xor
    float pm[2][4];
#pragma unroll
    for (int b2 = 0; b2 < 2; ++b2)
#pragma unroll
      for (int r = 0; r < 4; ++r)
        pm[b2][r] = fmaxf(fmaxf(s[b2][0][r], s[b2][1][r]),
                          fmaxf(s[b2][2][r], s[b2][3][r]));
#pragma unroll
    for (int m = 1; m < 16; m <<= 1)
#pragma unroll
      for (int b2 = 0; b2 < 2; ++b2)
#pragma unroll
        for (int r = 0; r < 4; ++r)
          pm[b2][r] = fmaxf(pm[b2][r], __shfl_xor(pm[b2][r], m, 64));

    // ---- online update + P (bf16) to swizzled LDS + row sum
    float rs[2][4];
#pragma unroll
    for (int b2 = 0; b2 < 2; ++b2)
#pragma unroll
      for (int r = 0; r < 4; ++r) {
        float mnew = fmaxf(mrun[b2][r], pm[b2][r]);
        float corr = exp2f(mrun[b2][r] - mnew);
        mrun[b2][r] = mnew;
        lrun[b2][r] *= corr;
#pragma unroll
        for (int df = 0; df < 4; ++df) o[df][b2][r] *= corr;
        int row = b2 * 16 + hi * 4 + r;
        float rsv = 0.f;
#pragma unroll
        for (int kf = 0; kf < 4; ++kf) {
          float p = exp2f(s[b2][kf][r] - mnew);
          rsv += p;
          *(bf16*)(pw + pswz(row, (kf * 16 + lo) * 2)) = (bf16)p;
        }
        rs[b2][r] = rsv;
      }
#pragma unroll
    for (int m = 1; m < 16; m <<= 1)
#pragma unroll
      for (int b2 = 0; b2 < 2; ++b2)
#pragma unroll
        for (int r = 0; r < 4; ++r)
          rs[b2][r] += __shfl_xor(rs[b2][r], m, 64);
#pragma unroll
    for (int b2 = 0; b2 < 2; ++b2)
#pragma unroll
      for (int r = 0; r < 4; ++r) lrun[b2][r] += rs[b2][r];

    // ---- PV: TWO 32-k steps (k is the MFMA reduction dim, 32 per mfma16).
    // pf elements: P[b2*16+lo][kk*32 + hi*8 + j]  (colbyte = kk*64 + hi*16)
    // vf elements: V[kb + kk*32 + hi*8 + j][df*16 + lo]
#pragma unroll
    for (int kk = 0; kk < 2; ++kk) {
      bf16x8 pf[2];
#pragma unroll
      for (int b2 = 0; b2 < 2; ++b2)
        pf[b2] = *(const bf16x8*)(pw + pswz(b2 * 16 + lo, kk * 64 + hi * 16));
#pragma unroll
      for (int df = 0; df < 4; ++df) {
        bf16x8 vf = *(const bf16x8*)&Vh[(df * 16 + lo) * SS + kb + kk * 32 + hi * 8];
#pragma unroll
        for (int b2 = 0; b2 < 2; ++b2)
          o[df][b2] = mfma16(pf[b2], vf, o[df][b2]);
      }
    }
  }

  int b = bh >> 4, h = bh & 15;
#pragma unroll
  for (int b2 = 0; b2 < 2; ++b2)
#pragma unroll
    for (int df = 0; df < 4; ++df)
#pragma unroll
      for (int r = 0; r < 4; ++r) {
        int q = q0w + b2 * 16 + hi * 4 + r;
        AO[(((long)(b * SS + q)) << 10) + h * DKK + df * 16 + lo] =
            (bf16)(o[df][b2][r] / lrun[b2][r]);
      }
}

// ---------------- launcher ----------------------------------------------------
extern "C" void kernel_launch(void* const* d_in, const int* in_sizes, int n_in,
                              void* d_out, int out_size, void* d_ws, size_t ws_size,
                              hipStream_t stream) {
  if (ws_size < (72ULL << 20)) return;

  const float* x  = (const float*)d_in[0];
  const float* Wq = (const float*)d_in[1];
  const float* bq = (const float*)d_in[2];
  const float* Wk = (const float*)d_in[3];
  const float* bk = (const float*)d_in[4];
  const float* Wv = (const float*)d_in[5];
  const float* bv = (const float*)d_in[6];
  const float* Wo = (const float*)d_in[7];
  const float* bo = (const float*)d_in[8];

  char* ws = (char*)d_ws;
  bf16* xb  = (bf16*)(ws);                     // 16 MB (later reused as AO)
  bf16* wtq = (bf16*)(ws + (16L << 20));
  bf16* wtk = (bf16*)(ws + (18L << 20));
  bf16* wtv = (bf16*)(ws + (20L << 20));
  bf16* wto = (bf16*)(ws + (22L << 20));
  bf16* Qb  = (bf16*)(ws + (24L << 20));
  bf16* Kb  = (bf16*)(ws + (40L << 20));
  bf16* VTb = (bf16*)(ws + (56L << 20));
  bf16* AO  = xb;

  cvt_kernel<<<(MTOT * DM) / (256 * 8), 256, 0, stream>>>(x, xb);
  transpose_cvt_kernel<<<dim3(32, 32, 4), dim3(32, 8), 0, stream>>>(
      Wq, Wk, Wv, Wo, wtq, wtk, wtv, wto);

  gemm_kernel<0><<<dim3(64, 8), 256, 0, stream>>>(xb, wtq, bq, (void*)Qb, QSC);
  gemm_kernel<0><<<dim3(64, 8), 256, 0, stream>>>(xb, wtk, bk, (void*)Kb, 1.0f);
  gemm_kernel<1><<<dim3(64, 8), 256, 0, stream>>>(xb, wtv, bv, (void*)VTb, 1.0f);

  attn_kernel<<<dim3(1024), 256, 0, stream>>>(Qb, Kb, VTb, AO);

  gemm_kernel<2><<<dim3(64, 8), 256, 0, stream>>>(AO, wto, bo, d_out, 1.0f);
}